// Round 4
// baseline (245.840 us; speedup 1.0000x reference)
//
#include <hip/hip_runtime.h>
#include <hip/hip_fp16.h>
#include <stdint.h>

#define B_  8
#define S_  2048
#define D_  512
#define K_  4096
#define N_  (B_ * S_)          // 16384 rows
#define NCB (K_ / 128)         // 32 code-blocks
#define NKB32 (D_ / 32)        // 16 k-blocks
#define MARGIN 0.014f          // 6sigma approx err + 127*ulp(512) key quantization

typedef _Float16 half8  __attribute__((ext_vector_type(8)));
typedef float    floatx4 __attribute__((ext_vector_type(4)));

// ---- workspace layout (bytes) ----
#define OFF_PK   0                                   // [N_][32] uint2 packed top-2 (4 MB)
#define OFF_EN   (OFF_PK + (size_t)N_ * NCB * 8)     // enorm [K_]
#define OFF_ZN   (OFF_EN + K_ * 4)                   // znorm [N_]
#define OFF_CNT  (OFF_ZN + N_ * 4)                   // counts [K_]
#define OFF_BL   (OFF_CNT + K_ * 4)                  // blockLoss [4096]
#define OFF_DC   (OFF_BL + 4096 * 4)                 // done-counter [1] (+pad)
#define OFF_ZH   (OFF_DC + 64)                       // zh packed [16][N_][32] f16 (16 MB)
#define OFF_EH   (OFF_ZH + (size_t)N_ * D_ * 2)      // eh packed [16][K_][32] f16 (4 MB)

__device__ __forceinline__ uint32_t umin32(uint32_t a, uint32_t b) { return a < b ? a : b; }
__device__ __forceinline__ uint32_t umax32(uint32_t a, uint32_t b) { return a > b ? a : b; }
__device__ __forceinline__ bool lexlt(float va, int ia, float vb, int ib) {
    return va < vb || (va == vb && ia < ib);
}

// async 16B global->LDS DMA; lds dst must be wave-uniform base + lane*16
__device__ __forceinline__ void load_lds16(const _Float16* g, _Float16* l) {
    __builtin_amdgcn_global_load_lds(
        (const __attribute__((address_space(1))) unsigned int*)(uintptr_t)g,
        (__attribute__((address_space(3))) unsigned int*)(uintptr_t)l,
        16, 0, 0);
}

// ---------------- kernel 1: fused prep ----------------
//  (a) row norms (order BIT-IDENTICAL to prior rounds -> preserves fp32 lattice),
//  (b) fp32->fp16 hi split, packed K-block-major + XOR chunk swizzle
//      (codebook scaled by 64, exact), (c) zero histogram counts + done ctr.
__global__ __launch_bounds__(256)
void vq_prep_kernel(const float* __restrict__ z, const float* __restrict__ cb,
                    _Float16* __restrict__ zh, _Float16* __restrict__ eh,
                    float* __restrict__ znorm, float* __restrict__ enorm,
                    int* __restrict__ counts, int* __restrict__ doneCnt) {
    const int t = threadIdx.x;
    if (blockIdx.x < 16) counts[blockIdx.x * 256 + t] = 0;
    if (blockIdx.x == 16 && t == 0) doneCnt[0] = 0;

    const size_t u = (size_t)blockIdx.x * 256 + t;
    const int c   = (int)(u & 63);     // lane / chunk id (8 consecutive k)
    const int row = (int)(u >> 6);
    const bool isZ = row < N_;
    const int n = isZ ? row : row - N_;
    const float* r = (isZ ? z : cb) + (size_t)n * D_;

    // (a) norm — identical order to prior rounds
    float s = 0.f;
    for (int j = c; j < D_; j += 64) { float v = r[j]; s += v * v; }
    #pragma unroll
    for (int m = 1; m < 64; m <<= 1) s += __shfl_xor(s, m, 64);
    if (c == 0) { if (isZ) znorm[n] = s; else enorm[n] = s; }

    // (b) hi split
    const float scale = isZ ? 1.0f : 64.0f;
    const float4 v0 = *(const float4*)(r + c * 8);
    const float4 v1 = *(const float4*)(r + c * 8 + 4);
    float a[8] = {v0.x, v0.y, v0.z, v0.w, v1.x, v1.y, v1.z, v1.w};
    half8 h;
    #pragma unroll
    for (int j = 0; j < 8; j++) h[j] = (_Float16)(a[j] * scale);
    const int kb = c >> 2, qd = c & 3;
    const int sw = qd ^ ((n >> 1) & 3);
    const size_t rows = isZ ? (size_t)N_ : (size_t)K_;
    const size_t off = (size_t)kb * rows * 32 + (size_t)n * 32 + (size_t)(sw << 3);
    *(half8*)((isZ ? zh : eh) + off) = h;
}

// ---------------- kernel 2: approx distance GEMM + per-tile packed top-2 ----------------
// round-0/3 structure (128x128 tile, 4 waves, ~3 blocks/CU) + T1 XCD-aware block
// remap: XCD k owns m-panels [k*16,(k+1)*16) x all 32 c-blocks, so each XCD's L2
// holds a 2MB zh slice + the 4MB eh; instantaneous WS/XCD drops 8MB -> ~4.5MB.
// Pure index remap: bit-identical pK.
__global__ __launch_bounds__(256, 4)
void vq_dist_kernel(const _Float16* __restrict__ zh, const _Float16* __restrict__ eh,
                    const float* __restrict__ enorm, const float* __restrict__ znorm,
                    uint2* __restrict__ pK) {
    __shared__ __align__(16) _Float16 sA[2][4096];   // 16 KB zh double-buffer
    __shared__ __align__(16) _Float16 sB[2][4096];   // 16 KB eh double-buffer
    __shared__ float sE[128], sZn[128];
    __shared__ uint2 cK[2][128];

    const int t  = threadIdx.x;
    // XCD swizzle: hw linear id round-robins XCDs; give XCD k a 16x32 block tile
    const int lin = (int)(blockIdx.y * gridDim.x + blockIdx.x);
    const int xcd = lin & 7, j = lin >> 3;           // j in [0,512)
    const int bxp = j & 31;                          // c-block (fast within XCD)
    const int byp = xcd * 16 + (j >> 5);             // m-panel
    const int c0 = bxp * 128;
    const int m0 = byp * 128;

    if (t < 128) { sE[t] = enorm[c0 + t]; sZn[t] = znorm[m0 + t]; }

    const int lane = t & 63, wid = t >> 6;
    const int wr = wid & 1, wc = wid >> 1;
    const int qd = lane >> 4, nl = lane & 15;
    const int sw8 = (qd ^ ((nl >> 1) & 3)) << 3;

    const size_t strideA = (size_t)N_ * 32;
    const size_t strideB = (size_t)K_ * 32;
    const _Float16* gA = zh + (size_t)m0 * 32 + (size_t)t * 8;   // per-thread global src
    const _Float16* gB = eh + (size_t)c0 * 32 + (size_t)t * 8;

    const int aoff = (wr * 64 + nl) * 32 + sw8;
    const int boff = (wc * 64 + nl) * 32 + sw8;

    floatx4 acc[4][4];
    #pragma unroll
    for (int i = 0; i < 4; i++)
        #pragma unroll
        for (int j2 = 0; j2 < 4; j2++) acc[i][j2] = (floatx4)0.f;

    auto stage = [&](int kb) {
        const _Float16* ga = gA + (size_t)kb * strideA;
        const _Float16* gb = gB + (size_t)kb * strideB;
        _Float16* la = sA[kb & 1] + t * 8;   // linear: wave-uniform base + lane*16B
        _Float16* lb = sB[kb & 1] + t * 8;
        load_lds16(ga, la);
        load_lds16(ga + 2048, la + 2048);
        load_lds16(gb, lb);
        load_lds16(gb + 2048, lb + 2048);
    };

    stage(0);

    for (int kb = 0; kb < NKB32; kb++) {
        __syncthreads();   // drains vmcnt: A/B(kb) landed; buf (kb+1)&1 free
        if (kb + 1 < NKB32) stage(kb + 1);   // async DMA, in flight across this step

        const _Float16* bh = sB[kb & 1] + boff;
        half8 b_h[4];
        #pragma unroll
        for (int s = 0; s < 4; s++)
            b_h[s] = *(const half8*)(bh + s * 512);
        const _Float16* ah = sA[kb & 1] + aoff;
        half8 a_h[4];
        #pragma unroll
        for (int s = 0; s < 4; s++)
            a_h[s] = *(const half8*)(ah + s * 512);
        #pragma unroll
        for (int i = 0; i < 4; i++)
            #pragma unroll
            for (int j2 = 0; j2 < 4; j2++)
                acc[i][j2] = __builtin_amdgcn_mfma_f32_16x16x32_f16(a_h[i], b_h[j2], acc[i][j2], 0, 0, 0);
    }

    // epilogue: packed-u32 top-2 per row over this 128-code block (byte-identical)
    uint32_t colc[4]; float se4[4];
    #pragma unroll
    for (int sn = 0; sn < 4; sn++) {
        const int cl = wc * 64 + sn * 16 + nl;
        colc[sn] = (uint32_t)cl;          // 7-bit block-local col
        se4[sn]  = sE[cl];
    }
    #pragma unroll
    for (int sm = 0; sm < 4; sm++) {
        #pragma unroll
        for (int reg = 0; reg < 4; reg++) {
            const int rm = wr * 64 + sm * 16 + qd * 4 + reg;
            const float zn = sZn[rm];
            uint32_t k0 = 0xFFFFFFFFu, k1 = 0xFFFFFFFFu;
            #pragma unroll
            for (int sn = 0; sn < 4; sn++) {
                const float v = fmaf(acc[sm][sn][reg], -0.03125f, zn + se4[sn]);
                const uint32_t key = (__float_as_uint(v) & 0xFFFFFF80u) | colc[sn];
                const uint32_t t1 = umax32(k0, key);
                k1 = umin32(k1, t1);
                k0 = umin32(k0, key);
            }
            #pragma unroll
            for (int msk = 1; msk <= 8; msk <<= 1) {
                const uint32_t o0 = (uint32_t)__shfl_xor((int)k0, msk, 64);
                const uint32_t o1 = (uint32_t)__shfl_xor((int)k1, msk, 64);
                const uint32_t n0 = umin32(k0, o0);
                k1 = umin32(umax32(k0, o0), umin32(k1, o1));
                k0 = n0;
            }
            if (nl == 0) { cK[wc][rm].x = k0; cK[wc][rm].y = k1; }
        }
    }
    __syncthreads();
    if (t < 128) {
        const uint2 a = cK[0][t], b = cK[1][t];
        uint2 r;
        r.x = umin32(a.x, b.x);
        r.y = umin32(umax32(a.x, b.x), umin32(a.y, b.y));
        pK[(size_t)(m0 + t) * NCB + bxp] = r;
    }
}

// ---------------- kernel 3: refine + gather + loss + histogram + fused finale ----------------
// Cross-block handoff uses ONLY coherent-point ops (device atomics + agent-scope
// load/store) — NO __threadfence (round-2's 4096x L2-writeback disaster). Each
// block: vmcnt drain (free; __syncthreads does it anyway) -> relaxed agent RMW on
// doneCnt. Last block reads counts/blockLoss with agent loads and emits scalars.
__global__ __launch_bounds__(256)
void vq_gather_kernel(const float* __restrict__ z, const float* __restrict__ cb,
                      const float* __restrict__ znorm, const float* __restrict__ enorm,
                      const uint2* __restrict__ pK,
                      float* __restrict__ out_zq, float* __restrict__ out_idx,
                      int* __restrict__ counts, float* __restrict__ blockLoss,
                      int* __restrict__ doneCnt,
                      float* __restrict__ out_loss, float* __restrict__ out_ppl) {
    const int lane = threadIdx.x & 63, wid = threadIdx.x >> 6;
    const int m = blockIdx.x * 4 + wid;

    uint32_t k0 = 0xFFFFFFFFu, k1 = 0xFFFFFFFFu;
    if (lane < NCB) {
        const uint2 kk = pK[(size_t)m * NCB + lane];
        k0 = kk.x; k1 = kk.y;
    }
    uint32_t g = k0;
    #pragma unroll
    for (int msk = 1; msk < 64; msk <<= 1) {
        const uint32_t o = (uint32_t)__shfl_xor((int)g, msk, 64);
        g = umin32(g, o);
    }
    const float gvf = __uint_as_float(g & 0xFFFFFF80u) + MARGIN;
    const bool f0 = (lane < NCB) && (__uint_as_float(k0 & 0xFFFFFF80u) <= gvf);
    const bool f1 = (lane < NCB) && (__uint_as_float(k1 & 0xFFFFFF80u) <= gvf);
    const unsigned long long b0 = __ballot(f0), b1 = __ballot(f1);
    int idx;
    if (__popcll(b0) + __popcll(b1) <= 1) {
        const unsigned long long bw = __ballot(k0 == g);
        idx = (int)__builtin_ctzll(bw) * 128 + (int)(g & 0x7Fu);
    } else {
        // exact fp32-lattice distance per candidate: d = fp32(fp32(zn+en) - 2*dot)
        const float zn = znorm[m];
        const float* zrow = z + (size_t)m * D_;
        float bestd = 1e30f; int besti = 0x7fffffff;
        #pragma unroll
        for (int slot = 0; slot < 2; slot++) {
            unsigned long long bm = slot ? b1 : b0;
            while (bm) {
                const int l = (int)__builtin_ctzll(bm); bm &= bm - 1;
                const uint32_t kx = (uint32_t)__shfl((int)(slot ? k1 : k0), l, 64);
                const int cand = l * 128 + (int)(kx & 0x7Fu);
                const float* crow = cb + (size_t)cand * D_;
                float s = 0.f;
                #pragma unroll
                for (int j = 0; j < 8; j++)
                    s += zrow[lane * 8 + j] * crow[lane * 8 + j];
                #pragma unroll
                for (int msk = 1; msk < 64; msk <<= 1) s += __shfl_xor(s, msk, 64);
                const float d = (zn + enorm[cand]) - 2.0f * s;
                if (lexlt(d, cand, bestd, besti)) { bestd = d; besti = cand; }
            }
        }
        idx = besti;
    }

    const float4* qrow  = (const float4*)(cb + (size_t)idx * D_);
    const float4* zrow4 = (const float4*)(z + (size_t)m * D_);
    float4*       orow  = (float4*)(out_zq + (size_t)m * D_);
    float lsum = 0.f;
    #pragma unroll
    for (int i = 0; i < 2; i++) {
        const int j = lane + i * 64;
        const float4 q  = qrow[j];
        const float4 zv = zrow4[j];
        float4 o;
        o.x = zv.x + (q.x - zv.x); o.y = zv.y + (q.y - zv.y);
        o.z = zv.z + (q.z - zv.z); o.w = zv.w + (q.w - zv.w);
        orow[j] = o;
        const float dx = zv.x - q.x, dy = zv.y - q.y, dz = zv.z - q.z, dw = zv.w - q.w;
        lsum += dx * dx + dy * dy + dz * dz + dw * dw;
    }
    #pragma unroll
    for (int msk = 1; msk < 64; msk <<= 1) lsum += __shfl_xor(lsum, msk, 64);

    if (lane == 0) {
        out_idx[m] = (float)idx;
        atomicAdd(&counts[idx], 1);   // device-scope, coherent point
    }
    __shared__ float wl[4];
    if (lane == 0) wl[wid] = lsum;
    __syncthreads();
    if (threadIdx.x == 0) {
        // agent-scope (device-coherent) store — NOT a fence
        __hip_atomic_store(&blockLoss[blockIdx.x], wl[0] + wl[1] + wl[2] + wl[3],
                           __ATOMIC_RELAXED, __HIP_MEMORY_SCOPE_AGENT);
    }
    // completion (vmcnt) of each thread's atomics/stores; syncthreads orders all
    // threads' drains before thread0's done-count bump. No cache maintenance.
    asm volatile("s_waitcnt vmcnt(0)" ::: "memory");
    __shared__ int sLast;
    __syncthreads();
    if (threadIdx.x == 0)
        sLast = (__hip_atomic_fetch_add(doneCnt, 1, __ATOMIC_RELAXED,
                                        __HIP_MEMORY_SCOPE_AGENT) == (N_ / 4) - 1) ? 1 : 0;
    __syncthreads();
    if (sLast) {
        // all other blocks completed their coherent-point writes before bumping
        __shared__ float sl[256], se[256];
        const int tt = threadIdx.x;
        float ls = 0.f, es = 0.f;
        for (int i = tt; i < N_ / 4; i += 256)
            ls += __hip_atomic_load(&blockLoss[i], __ATOMIC_RELAXED, __HIP_MEMORY_SCOPE_AGENT);
        for (int k = tt; k < K_; k += 256) {
            const int cv = __hip_atomic_load(&counts[k], __ATOMIC_RELAXED, __HIP_MEMORY_SCOPE_AGENT);
            const float p = (float)cv / (float)N_;
            es += p * logf(p + 1e-10f);
        }
        sl[tt] = ls; se[tt] = es;
        __syncthreads();
        for (int s = 128; s > 0; s >>= 1) {
            if (tt < s) { sl[tt] += sl[tt + s]; se[tt] += se[tt + s]; }
            __syncthreads();
        }
        if (tt == 0) {
            out_loss[0] = 0.25f * (sl[0] / (float)((size_t)N_ * D_));
            out_ppl[0]  = expf(-se[0]);
        }
    }
}

extern "C" void kernel_launch(void* const* d_in, const int* in_sizes, int n_in,
                              void* d_out, int out_size, void* d_ws, size_t ws_size,
                              hipStream_t stream) {
    const float* z  = (const float*)d_in[0];
    const float* cb = (const float*)d_in[1];
    float* out = (float*)d_out;

    char* ws = (char*)d_ws;
    uint2*    pK        = (uint2*)   (ws + OFF_PK);
    float*    enorm     = (float*)   (ws + OFF_EN);
    float*    znorm     = (float*)   (ws + OFF_ZN);
    int*      counts    = (int*)     (ws + OFF_CNT);
    float*    blockLoss = (float*)   (ws + OFF_BL);
    int*      doneCnt   = (int*)     (ws + OFF_DC);
    _Float16* zh        = (_Float16*)(ws + OFF_ZH);
    _Float16* eh        = (_Float16*)(ws + OFF_EH);

    float* out_zq   = out;                         // [N_*D_]
    float* out_loss = out + (size_t)N_ * D_;       // [1]
    float* out_idx  = out_loss + 1;                // [N_]
    float* out_ppl  = out_idx + N_;                // [1]

    vq_prep_kernel<<<(N_ + K_) * 64 / 256, 256, 0, stream>>>(z, cb, zh, eh,
                                                             znorm, enorm, counts, doneCnt);

    dim3 grid(K_ / 128, N_ / 128);   // remapped in-kernel: 16x32 block tile per XCD
    vq_dist_kernel<<<grid, 256, 0, stream>>>(zh, eh, enorm, znorm, pK);

    vq_gather_kernel<<<N_ / 4, 256, 0, stream>>>(z, cb, znorm, enorm, pK,
                                                 out_zq, out_idx, counts, blockLoss,
                                                 doneCnt, out_loss, out_ppl);
}

// Round 5
// 222.909 us; speedup vs baseline: 1.1029x; 1.1029x over previous
//
#include <hip/hip_runtime.h>
#include <hip/hip_fp16.h>
#include <stdint.h>

#define B_  8
#define S_  2048
#define D_  512
#define K_  4096
#define N_  (B_ * S_)          // 16384 rows
#define NCB (K_ / 128)         // 32 code-blocks
#define NKB32 (D_ / 32)        // 16 k-blocks
#define MARGIN 0.014f          // 6sigma approx err + 127*ulp(512) key quantization

typedef _Float16 half8  __attribute__((ext_vector_type(8)));
typedef float    floatx4 __attribute__((ext_vector_type(4)));

// ---- workspace layout (bytes) ----
#define OFF_PK   0                                   // [N_][32] uint2 packed top-2 (4 MB)
#define OFF_EN   (OFF_PK + (size_t)N_ * NCB * 8)     // enorm [K_]
#define OFF_ZN   (OFF_EN + K_ * 4)                   // znorm [N_]
#define OFF_CNT  (OFF_ZN + N_ * 4)                   // counts [K_]
#define OFF_BL   (OFF_CNT + K_ * 4)                  // blockLoss [4096]
#define OFF_ZH   (OFF_BL + 4096 * 4)                 // zh packed [16][N_][32] f16 (16 MB)
#define OFF_EH   (OFF_ZH + (size_t)N_ * D_ * 2)      // eh packed [16][K_][32] f16 (4 MB)

__device__ __forceinline__ uint32_t umin32(uint32_t a, uint32_t b) { return a < b ? a : b; }
__device__ __forceinline__ uint32_t umax32(uint32_t a, uint32_t b) { return a > b ? a : b; }
__device__ __forceinline__ bool lexlt(float va, int ia, float vb, int ib) {
    return va < vb || (va == vb && ia < ib);
}

// async 16B global->LDS DMA; lds dst must be wave-uniform base + lane*16
__device__ __forceinline__ void load_lds16(const _Float16* g, _Float16* l) {
    __builtin_amdgcn_global_load_lds(
        (const __attribute__((address_space(1))) unsigned int*)(uintptr_t)g,
        (__attribute__((address_space(3))) unsigned int*)(uintptr_t)l,
        16, 0, 0);
}

// ---------------- kernel 1: fused prep (LDS-transposed coalesced stores) ----------------
// Old prep scattered each wave's 1KB store into 16x64B fragments (kb-plane stride
// 1-4MB) -> ~327K partial-line write transactions, ~4x over roofline (inferred
// ~55-70us from round-2 subtraction). New: each block owns 32 rows; norms keep the
// BIT-IDENTICAL scalar stride-64 order; convert phase writes the same bytes into a
// 32KB LDS image (layout == final global layout per kb-plane); store phase streams
// 16 x 2KB contiguous chunks, fully coalesced. zh/eh/norm bytes identical.
__global__ __launch_bounds__(256)
void vq_prep_kernel(const float* __restrict__ z, const float* __restrict__ cb,
                    _Float16* __restrict__ zh, _Float16* __restrict__ eh,
                    float* __restrict__ znorm, float* __restrict__ enorm,
                    int* __restrict__ counts) {
    __shared__ __align__(16) char sT[16 * 2064];   // 16 kb-planes x (32 rows x 64B) + 16B pad

    const int t = threadIdx.x;
    if (blockIdx.x < 16) counts[blockIdx.x * 256 + t] = 0;

    const int bx  = (int)blockIdx.x;
    const bool isZ = bx < (N_ / 32);
    const int n0  = (isZ ? bx : bx - N_ / 32) * 32;
    const float* src = (isZ ? z : cb);
    const size_t rows = isZ ? (size_t)N_ : (size_t)K_;
    _Float16* dst = isZ ? zh : eh;
    const float scale = isZ ? 1.0f : 64.0f;

    const int lane = t & 63, wid = t >> 6;

    // phase 1: norms — scalar stride-64 loop + butterfly, BIT-IDENTICAL order
    #pragma unroll
    for (int q = 0; q < 8; q++) {
        const int nl = wid * 8 + q;
        const float* r = src + (size_t)(n0 + nl) * D_;
        float s = 0.f;
        for (int j = lane; j < D_; j += 64) { float v = r[j]; s += v * v; }
        #pragma unroll
        for (int m = 1; m < 64; m <<= 1) s += __shfl_xor(s, m, 64);
        if (lane == 0) { if (isZ) znorm[n0 + nl] = s; else enorm[n0 + nl] = s; }
    }

    // phase 2: convert + place into LDS at final layout (plane stride 2064B: the
    // 16B pad staggers kb-planes across banks)
    #pragma unroll
    for (int q = 0; q < 8; q++) {
        const int nl = wid * 8 + q;
        const int n  = n0 + nl;
        const float* r = src + (size_t)n * D_;
        const float4 v0 = *(const float4*)(r + lane * 8);
        const float4 v1 = *(const float4*)(r + lane * 8 + 4);
        float a[8] = {v0.x, v0.y, v0.z, v0.w, v1.x, v1.y, v1.z, v1.w};
        half8 h;
        #pragma unroll
        for (int j = 0; j < 8; j++) h[j] = (_Float16)(a[j] * scale);
        const int kb = lane >> 2, qd = lane & 3;
        const int sw = qd ^ ((n >> 1) & 3);
        *(half8*)(sT + kb * 2064 + nl * 64 + sw * 16) = h;
    }
    __syncthreads();

    // phase 3: stream out — per kb-plane 2KB contiguous (32 rows x 32 halfs)
    #pragma unroll
    for (int it = 0; it < 8; it++) {
        const int q  = it * 256 + t;        // 2048 x 16B chunks
        const int kb = q >> 7;              // 128 chunks per plane
        const int w  = q & 127;
        const uint4 d = *(const uint4*)(sT + kb * 2064 + w * 16);
        *(uint4*)(dst + (size_t)kb * rows * 32 + (size_t)n0 * 32 + (size_t)w * 8) = d;
    }
}

// ---------------- kernel 2: approx distance GEMM + per-tile packed top-2 ----------------
// (round-0 version verbatim — best measured 90.0us; B via registers, default raster)
__global__ __launch_bounds__(256, 4)
void vq_dist_kernel(const _Float16* __restrict__ zh, const _Float16* __restrict__ eh,
                    const float* __restrict__ enorm, const float* __restrict__ znorm,
                    uint2* __restrict__ pK) {
    __shared__ _Float16 sA[2][4096];           // 16 KB zh double-buffer
    __shared__ float sE[128], sZn[128];
    __shared__ uint2 cK[2][128];

    const int t  = threadIdx.x;
    const int c0 = blockIdx.x * 128;   // x = c-fast: 4MB eh L2-resident
    const int m0 = blockIdx.y * 128;

    if (t < 128) { sE[t] = enorm[c0 + t]; sZn[t] = znorm[m0 + t]; }

    const int lane = t & 63, wid = t >> 6;
    const int wr = wid & 1, wc = wid >> 1;
    const int qd = lane >> 4, nl = lane & 15;
    const int sw8 = (qd ^ ((nl >> 1) & 3)) << 3;

    const _Float16* gsrc = zh + (size_t)m0 * 32 + (size_t)(wid * 2) * 512 + (size_t)lane * 8;
    const size_t strideA = (size_t)N_ * 32;
    const size_t strideB = (size_t)K_ * 32;
    const _Float16* bptr = eh + (size_t)c0 * 32 + (size_t)((wc * 64 + nl) * 32 + sw8);
    const int aoff = (wr * 64 + nl) * 32 + sw8;

    floatx4 acc[4][4];
    #pragma unroll
    for (int i = 0; i < 4; i++)
        #pragma unroll
        for (int j = 0; j < 4; j++) acc[i][j] = (floatx4)0.f;

    #pragma unroll
    for (int g = 0; g < 2; g++)
        load_lds16(gsrc + g * 512, sA[0] + wid * 2 * 512 + g * 512);

    for (int kb = 0; kb < NKB32; kb++) {
        __syncthreads();   // drains vmcnt: A(kb) landed; buf (kb+1)&1 free

        half8 b_h[4];
        #pragma unroll
        for (int s = 0; s < 4; s++)
            b_h[s] = *(const half8*)(bptr + s * 512);
        if (kb + 1 < NKB32) {
            const _Float16* gk = gsrc + (size_t)(kb + 1) * strideA;
            _Float16* ld = sA[(kb + 1) & 1] + wid * 2 * 512;
            #pragma unroll
            for (int g = 0; g < 2; g++)
                load_lds16(gk + g * 512, ld + g * 512);
        }
        const _Float16* ah = sA[kb & 1] + aoff;
        half8 a_h[4];
        #pragma unroll
        for (int s = 0; s < 4; s++)
            a_h[s] = *(const half8*)(ah + s * 512);
        #pragma unroll
        for (int i = 0; i < 4; i++)
            #pragma unroll
            for (int j = 0; j < 4; j++)
                acc[i][j] = __builtin_amdgcn_mfma_f32_16x16x32_f16(a_h[i], b_h[j], acc[i][j], 0, 0, 0);
        bptr += strideB;
    }

    // epilogue: packed-u32 top-2 per row over this 128-code block
    uint32_t colc[4]; float se4[4];
    #pragma unroll
    for (int sn = 0; sn < 4; sn++) {
        const int cl = wc * 64 + sn * 16 + nl;
        colc[sn] = (uint32_t)cl;          // 7-bit block-local col
        se4[sn]  = sE[cl];
    }
    #pragma unroll
    for (int sm = 0; sm < 4; sm++) {
        #pragma unroll
        for (int reg = 0; reg < 4; reg++) {
            const int rm = wr * 64 + sm * 16 + qd * 4 + reg;
            const float zn = sZn[rm];
            uint32_t k0 = 0xFFFFFFFFu, k1 = 0xFFFFFFFFu;
            #pragma unroll
            for (int sn = 0; sn < 4; sn++) {
                const float v = fmaf(acc[sm][sn][reg], -0.03125f, zn + se4[sn]);
                const uint32_t key = (__float_as_uint(v) & 0xFFFFFF80u) | colc[sn];
                const uint32_t t1 = umax32(k0, key);
                k1 = umin32(k1, t1);
                k0 = umin32(k0, key);
            }
            #pragma unroll
            for (int msk = 1; msk <= 8; msk <<= 1) {
                const uint32_t o0 = (uint32_t)__shfl_xor((int)k0, msk, 64);
                const uint32_t o1 = (uint32_t)__shfl_xor((int)k1, msk, 64);
                const uint32_t n0 = umin32(k0, o0);
                k1 = umin32(umax32(k0, o0), umin32(k1, o1));
                k0 = n0;
            }
            if (nl == 0) { cK[wc][rm].x = k0; cK[wc][rm].y = k1; }
        }
    }
    __syncthreads();
    if (t < 128) {
        const uint2 a = cK[0][t], b = cK[1][t];
        uint2 r;
        r.x = umin32(a.x, b.x);
        r.y = umin32(umax32(a.x, b.x), umin32(a.y, b.y));
        pK[(size_t)(m0 + t) * NCB + blockIdx.x] = r;
    }
}

// ---------------- kernel 3: refine + gather + loss partials + histogram ----------------
// (round-0 version verbatim — no fences, no fused finale)
__global__ __launch_bounds__(256)
void vq_gather_kernel(const float* __restrict__ z, const float* __restrict__ cb,
                      const float* __restrict__ znorm, const float* __restrict__ enorm,
                      const uint2* __restrict__ pK,
                      float* __restrict__ out_zq, float* __restrict__ out_idx,
                      int* __restrict__ counts, float* __restrict__ blockLoss) {
    const int lane = threadIdx.x & 63, wid = threadIdx.x >> 6;
    const int m = blockIdx.x * 4 + wid;

    uint32_t k0 = 0xFFFFFFFFu, k1 = 0xFFFFFFFFu;
    if (lane < NCB) {
        const uint2 kk = pK[(size_t)m * NCB + lane];
        k0 = kk.x; k1 = kk.y;
    }
    uint32_t g = k0;
    #pragma unroll
    for (int msk = 1; msk < 64; msk <<= 1) {
        const uint32_t o = (uint32_t)__shfl_xor((int)g, msk, 64);
        g = umin32(g, o);
    }
    const float gvf = __uint_as_float(g & 0xFFFFFF80u) + MARGIN;
    const bool f0 = (lane < NCB) && (__uint_as_float(k0 & 0xFFFFFF80u) <= gvf);
    const bool f1 = (lane < NCB) && (__uint_as_float(k1 & 0xFFFFFF80u) <= gvf);
    const unsigned long long b0 = __ballot(f0), b1 = __ballot(f1);
    int idx;
    if (__popcll(b0) + __popcll(b1) <= 1) {
        const unsigned long long bw = __ballot(k0 == g);
        idx = (int)__builtin_ctzll(bw) * 128 + (int)(g & 0x7Fu);
    } else {
        // exact fp32-lattice distance per candidate: d = fp32(fp32(zn+en) - 2*dot)
        const float zn = znorm[m];
        const float* zrow = z + (size_t)m * D_;
        float bestd = 1e30f; int besti = 0x7fffffff;
        #pragma unroll
        for (int slot = 0; slot < 2; slot++) {
            unsigned long long bm = slot ? b1 : b0;
            while (bm) {
                const int l = (int)__builtin_ctzll(bm); bm &= bm - 1;
                const uint32_t kx = (uint32_t)__shfl((int)(slot ? k1 : k0), l, 64);
                const int cand = l * 128 + (int)(kx & 0x7Fu);
                const float* crow = cb + (size_t)cand * D_;
                float s = 0.f;
                #pragma unroll
                for (int j = 0; j < 8; j++)
                    s += zrow[lane * 8 + j] * crow[lane * 8 + j];
                #pragma unroll
                for (int msk = 1; msk < 64; msk <<= 1) s += __shfl_xor(s, msk, 64);
                const float d = (zn + enorm[cand]) - 2.0f * s;
                if (lexlt(d, cand, bestd, besti)) { bestd = d; besti = cand; }
            }
        }
        idx = besti;
    }

    const float4* qrow  = (const float4*)(cb + (size_t)idx * D_);
    const float4* zrow4 = (const float4*)(z + (size_t)m * D_);
    float4*       orow  = (float4*)(out_zq + (size_t)m * D_);
    float lsum = 0.f;
    #pragma unroll
    for (int i = 0; i < 2; i++) {
        const int j = lane + i * 64;
        const float4 q  = qrow[j];
        const float4 zv = zrow4[j];
        float4 o;
        o.x = zv.x + (q.x - zv.x); o.y = zv.y + (q.y - zv.y);
        o.z = zv.z + (q.z - zv.z); o.w = zv.w + (q.w - zv.w);
        orow[j] = o;
        const float dx = zv.x - q.x, dy = zv.y - q.y, dz = zv.z - q.z, dw = zv.w - q.w;
        lsum += dx * dx + dy * dy + dz * dz + dw * dw;
    }
    #pragma unroll
    for (int msk = 1; msk < 64; msk <<= 1) lsum += __shfl_xor(lsum, msk, 64);

    if (lane == 0) {
        out_idx[m] = (float)idx;
        atomicAdd(&counts[idx], 1);
    }
    __shared__ float wl[4];
    if (lane == 0) wl[wid] = lsum;
    __syncthreads();
    if (threadIdx.x == 0) blockLoss[blockIdx.x] = wl[0] + wl[1] + wl[2] + wl[3];
}

// ---------------- kernel 4: scalars (loss, perplexity) ----------------
__global__ void vq_final_kernel(const int* __restrict__ counts,
                                const float* __restrict__ blockLoss,
                                float* __restrict__ out_loss, float* __restrict__ out_ppl) {
    __shared__ float sl[256], se[256];
    const int t = threadIdx.x;
    float ls = 0.f, es = 0.f;
    for (int i = t; i < N_ / 4; i += 256) ls += blockLoss[i];
    for (int k = t; k < K_; k += 256) {
        const float p = (float)counts[k] / (float)N_;
        es += p * logf(p + 1e-10f);
    }
    sl[t] = ls; se[t] = es;
    __syncthreads();
    for (int s = 128; s > 0; s >>= 1) {
        if (t < s) { sl[t] += sl[t + s]; se[t] += se[t + s]; }
        __syncthreads();
    }
    if (t == 0) {
        out_loss[0] = 0.25f * (sl[0] / (float)((size_t)N_ * D_));
        out_ppl[0]  = expf(-se[0]);
    }
}

extern "C" void kernel_launch(void* const* d_in, const int* in_sizes, int n_in,
                              void* d_out, int out_size, void* d_ws, size_t ws_size,
                              hipStream_t stream) {
    const float* z  = (const float*)d_in[0];
    const float* cb = (const float*)d_in[1];
    float* out = (float*)d_out;

    char* ws = (char*)d_ws;
    uint2*    pK        = (uint2*)   (ws + OFF_PK);
    float*    enorm     = (float*)   (ws + OFF_EN);
    float*    znorm     = (float*)   (ws + OFF_ZN);
    int*      counts    = (int*)     (ws + OFF_CNT);
    float*    blockLoss = (float*)   (ws + OFF_BL);
    _Float16* zh        = (_Float16*)(ws + OFF_ZH);
    _Float16* eh        = (_Float16*)(ws + OFF_EH);

    float* out_zq   = out;                         // [N_*D_]
    float* out_loss = out + (size_t)N_ * D_;       // [1]
    float* out_idx  = out_loss + 1;                // [N_]
    float* out_ppl  = out_idx + N_;                // [1]

    vq_prep_kernel<<<(N_ + K_) / 32, 256, 0, stream>>>(z, cb, zh, eh,
                                                       znorm, enorm, counts);

    dim3 grid(K_ / 128, N_ / 128);   // x = c-block fast: eh L2-resident
    vq_dist_kernel<<<grid, 256, 0, stream>>>(zh, eh, enorm, znorm, pK);

    vq_gather_kernel<<<N_ / 4, 256, 0, stream>>>(z, cb, znorm, enorm, pK,
                                                 out_zq, out_idx, counts, blockLoss);

    vq_final_kernel<<<1, 256, 0, stream>>>(counts, blockLoss, out_loss, out_ppl);
}

// Round 6
// 200.020 us; speedup vs baseline: 1.2291x; 1.1144x over previous
//
#include <hip/hip_runtime.h>
#include <hip/hip_fp16.h>
#include <stdint.h>

#define B_  8
#define S_  2048
#define D_  512
#define K_  4096
#define N_  (B_ * S_)          // 16384 rows
#define NCB (K_ / 128)         // 32 code-blocks
#define NKB32 (D_ / 32)        // 16 k-blocks
#define MARGIN 0.014f          // 6sigma approx err + 127*ulp(512) key quantization

typedef _Float16 half8  __attribute__((ext_vector_type(8)));
typedef float    floatx4 __attribute__((ext_vector_type(4)));

// ---- workspace layout (bytes) ----
#define OFF_PK   0                                   // [N_][32] uint2 packed top-2 (4 MB)
#define OFF_EN   (OFF_PK + (size_t)N_ * NCB * 8)     // enorm [K_]
#define OFF_ZN   (OFF_EN + K_ * 4)                   // znorm [N_]
#define OFF_CNT  (OFF_ZN + N_ * 4)                   // counts [K_]
#define OFF_BL   (OFF_CNT + K_ * 4)                  // blockLoss [4096]
#define OFF_ZH   (OFF_BL + 4096 * 4)                 // zh packed [16][N_][32] f16 (16 MB)
#define OFF_EH   (OFF_ZH + (size_t)N_ * D_ * 2)      // eh packed [16][K_][32] f16 (4 MB)

__device__ __forceinline__ uint32_t umin32(uint32_t a, uint32_t b) { return a < b ? a : b; }
__device__ __forceinline__ uint32_t umax32(uint32_t a, uint32_t b) { return a > b ? a : b; }
__device__ __forceinline__ bool lexlt(float va, int ia, float vb, int ib) {
    return va < vb || (va == vb && ia < ib);
}

// async 16B global->LDS DMA; lds dst must be wave-uniform base + lane*16
__device__ __forceinline__ void load_lds16(const _Float16* g, _Float16* l) {
    __builtin_amdgcn_global_load_lds(
        (const __attribute__((address_space(1))) unsigned int*)(uintptr_t)g,
        (__attribute__((address_space(3))) unsigned int*)(uintptr_t)l,
        16, 0, 0);
}

// ---------------- kernel 1: fused prep (round-0 verbatim) ----------------
//  (a) row norms (order BIT-IDENTICAL across rounds -> preserves fp32 lattice),
//  (b) fp32->fp16 hi split, packed K-block-major + XOR chunk swizzle
//      (codebook scaled by 64, exact), (c) zero the histogram counts.
__global__ __launch_bounds__(256)
void vq_prep_kernel(const float* __restrict__ z, const float* __restrict__ cb,
                    _Float16* __restrict__ zh, _Float16* __restrict__ eh,
                    float* __restrict__ znorm, float* __restrict__ enorm,
                    int* __restrict__ counts) {
    const int t = threadIdx.x;
    if (blockIdx.x < 16) counts[blockIdx.x * 256 + t] = 0;

    const size_t u = (size_t)blockIdx.x * 256 + t;
    const int c   = (int)(u & 63);     // lane / chunk id (8 consecutive k)
    const int row = (int)(u >> 6);
    const bool isZ = row < N_;
    const int n = isZ ? row : row - N_;
    const float* r = (isZ ? z : cb) + (size_t)n * D_;

    // (a) norm — identical order across rounds
    float s = 0.f;
    for (int j = c; j < D_; j += 64) { float v = r[j]; s += v * v; }
    #pragma unroll
    for (int m = 1; m < 64; m <<= 1) s += __shfl_xor(s, m, 64);
    if (c == 0) { if (isZ) znorm[n] = s; else enorm[n] = s; }

    // (b) hi split
    const float scale = isZ ? 1.0f : 64.0f;
    const float4 v0 = *(const float4*)(r + c * 8);
    const float4 v1 = *(const float4*)(r + c * 8 + 4);
    float a[8] = {v0.x, v0.y, v0.z, v0.w, v1.x, v1.y, v1.z, v1.w};
    half8 h;
    #pragma unroll
    for (int j = 0; j < 8; j++) h[j] = (_Float16)(a[j] * scale);
    const int kb = c >> 2, qd = c & 3;
    const int sw = qd ^ ((n >> 1) & 3);
    const size_t rows = isZ ? (size_t)N_ : (size_t)K_;
    const size_t off = (size_t)kb * rows * 32 + (size_t)n * 32 + (size_t)(sw << 3);
    *(half8*)((isZ ? zh : eh) + off) = h;
}

// ---------------- kernel 2: approx distance GEMM + per-tile packed top-2 ----------------
// round-0 structure with BK=64: 32 MFMA per barrier (2x fewer vmcnt(0) drains,
// matching the m97/AITER cadence). A-tile double-buffer 2x16KB; B via registers.
// K-accumulation order kb=0..15 sequential, identical inputs -> pK bit-identical.
__global__ __launch_bounds__(256, 4)
void vq_dist_kernel(const _Float16* __restrict__ zh, const _Float16* __restrict__ eh,
                    const float* __restrict__ enorm, const float* __restrict__ znorm,
                    uint2* __restrict__ pK) {
    __shared__ __align__(16) _Float16 sA[2][8192];   // 32 KB zh double-buffer (64-k tile)
    __shared__ float sE[128], sZn[128];
    __shared__ uint2 cK[2][128];

    const int t  = threadIdx.x;
    const int c0 = blockIdx.x * 128;   // x = c-fast: 4MB eh L2-resident
    const int m0 = blockIdx.y * 128;

    if (t < 128) { sE[t] = enorm[c0 + t]; sZn[t] = znorm[m0 + t]; }

    const int lane = t & 63, wid = t >> 6;
    const int wr = wid & 1, wc = wid >> 1;
    const int qd = lane >> 4, nl = lane & 15;
    const int sw8 = (qd ^ ((nl >> 1) & 3)) << 3;

    const size_t strideA = (size_t)N_ * 32;
    const size_t strideB = (size_t)K_ * 32;
    const _Float16* gsrc = zh + (size_t)m0 * 32 + (size_t)(wid * 2) * 512 + (size_t)lane * 8;
    const _Float16* bptr = eh + (size_t)c0 * 32 + (size_t)((wc * 64 + nl) * 32 + sw8);
    const int aoff = (wr * 64 + nl) * 32 + sw8;

    floatx4 acc[4][4];
    #pragma unroll
    for (int i = 0; i < 4; i++)
        #pragma unroll
        for (int j = 0; j < 4; j++) acc[i][j] = (floatx4)0.f;

    // stage one 64-k A-tile (2 kb-planes) into buffer b
    auto stageA = [&](int st, int b) {
        #pragma unroll
        for (int p = 0; p < 2; p++) {
            const _Float16* gk = gsrc + (size_t)(st * 2 + p) * strideA;
            _Float16* ld = sA[b] + p * 4096 + wid * 2 * 512;
            #pragma unroll
            for (int g = 0; g < 2; g++)
                load_lds16(gk + g * 512, ld + g * 512);
        }
    };

    stageA(0, 0);

    for (int st = 0; st < NKB32 / 2; st++) {   // 8 steps of BK=64
        __syncthreads();   // drains vmcnt: A-tile(st) landed; other buffer free
        if (st + 1 < NKB32 / 2) stageA(st + 1, (st + 1) & 1);

        #pragma unroll
        for (int p = 0; p < 2; p++) {          // two 32-k sub-steps, K-order preserved
            const _Float16* bp = bptr + (size_t)(st * 2 + p) * strideB;
            half8 b_h[4];
            #pragma unroll
            for (int s = 0; s < 4; s++)
                b_h[s] = *(const half8*)(bp + s * 512);
            const _Float16* ah = sA[st & 1] + p * 4096 + aoff;
            half8 a_h[4];
            #pragma unroll
            for (int s = 0; s < 4; s++)
                a_h[s] = *(const half8*)(ah + s * 512);
            #pragma unroll
            for (int i = 0; i < 4; i++)
                #pragma unroll
                for (int j = 0; j < 4; j++)
                    acc[i][j] = __builtin_amdgcn_mfma_f32_16x16x32_f16(a_h[i], b_h[j], acc[i][j], 0, 0, 0);
        }
    }

    // epilogue: packed-u32 top-2 per row over this 128-code block (byte-identical)
    uint32_t colc[4]; float se4[4];
    #pragma unroll
    for (int sn = 0; sn < 4; sn++) {
        const int cl = wc * 64 + sn * 16 + nl;
        colc[sn] = (uint32_t)cl;          // 7-bit block-local col
        se4[sn]  = sE[cl];
    }
    #pragma unroll
    for (int sm = 0; sm < 4; sm++) {
        #pragma unroll
        for (int reg = 0; reg < 4; reg++) {
            const int rm = wr * 64 + sm * 16 + qd * 4 + reg;
            const float zn = sZn[rm];
            uint32_t k0 = 0xFFFFFFFFu, k1 = 0xFFFFFFFFu;
            #pragma unroll
            for (int sn = 0; sn < 4; sn++) {
                const float v = fmaf(acc[sm][sn][reg], -0.03125f, zn + se4[sn]);
                const uint32_t key = (__float_as_uint(v) & 0xFFFFFF80u) | colc[sn];
                const uint32_t t1 = umax32(k0, key);
                k1 = umin32(k1, t1);
                k0 = umin32(k0, key);
            }
            #pragma unroll
            for (int msk = 1; msk <= 8; msk <<= 1) {
                const uint32_t o0 = (uint32_t)__shfl_xor((int)k0, msk, 64);
                const uint32_t o1 = (uint32_t)__shfl_xor((int)k1, msk, 64);
                const uint32_t n0 = umin32(k0, o0);
                k1 = umin32(umax32(k0, o0), umin32(k1, o1));
                k0 = n0;
            }
            if (nl == 0) { cK[wc][rm].x = k0; cK[wc][rm].y = k1; }
        }
    }
    __syncthreads();
    if (t < 128) {
        const uint2 a = cK[0][t], b = cK[1][t];
        uint2 r;
        r.x = umin32(a.x, b.x);
        r.y = umin32(umax32(a.x, b.x), umin32(a.y, b.y));
        pK[(size_t)(m0 + t) * NCB + blockIdx.x] = r;
    }
}

// ---------------- kernel 3: refine + gather + loss partials + histogram ----------------
// (round-0 verbatim — no fences, no fused finale)
__global__ __launch_bounds__(256)
void vq_gather_kernel(const float* __restrict__ z, const float* __restrict__ cb,
                      const float* __restrict__ znorm, const float* __restrict__ enorm,
                      const uint2* __restrict__ pK,
                      float* __restrict__ out_zq, float* __restrict__ out_idx,
                      int* __restrict__ counts, float* __restrict__ blockLoss) {
    const int lane = threadIdx.x & 63, wid = threadIdx.x >> 6;
    const int m = blockIdx.x * 4 + wid;

    uint32_t k0 = 0xFFFFFFFFu, k1 = 0xFFFFFFFFu;
    if (lane < NCB) {
        const uint2 kk = pK[(size_t)m * NCB + lane];
        k0 = kk.x; k1 = kk.y;
    }
    uint32_t g = k0;
    #pragma unroll
    for (int msk = 1; msk < 64; msk <<= 1) {
        const uint32_t o = (uint32_t)__shfl_xor((int)g, msk, 64);
        g = umin32(g, o);
    }
    const float gvf = __uint_as_float(g & 0xFFFFFF80u) + MARGIN;
    const bool f0 = (lane < NCB) && (__uint_as_float(k0 & 0xFFFFFF80u) <= gvf);
    const bool f1 = (lane < NCB) && (__uint_as_float(k1 & 0xFFFFFF80u) <= gvf);
    const unsigned long long b0 = __ballot(f0), b1 = __ballot(f1);
    int idx;
    if (__popcll(b0) + __popcll(b1) <= 1) {
        const unsigned long long bw = __ballot(k0 == g);
        idx = (int)__builtin_ctzll(bw) * 128 + (int)(g & 0x7Fu);
    } else {
        // exact fp32-lattice distance per candidate: d = fp32(fp32(zn+en) - 2*dot)
        const float zn = znorm[m];
        const float* zrow = z + (size_t)m * D_;
        float bestd = 1e30f; int besti = 0x7fffffff;
        #pragma unroll
        for (int slot = 0; slot < 2; slot++) {
            unsigned long long bm = slot ? b1 : b0;
            while (bm) {
                const int l = (int)__builtin_ctzll(bm); bm &= bm - 1;
                const uint32_t kx = (uint32_t)__shfl((int)(slot ? k1 : k0), l, 64);
                const int cand = l * 128 + (int)(kx & 0x7Fu);
                const float* crow = cb + (size_t)cand * D_;
                float s = 0.f;
                #pragma unroll
                for (int j = 0; j < 8; j++)
                    s += zrow[lane * 8 + j] * crow[lane * 8 + j];
                #pragma unroll
                for (int msk = 1; msk < 64; msk <<= 1) s += __shfl_xor(s, msk, 64);
                const float d = (zn + enorm[cand]) - 2.0f * s;
                if (lexlt(d, cand, bestd, besti)) { bestd = d; besti = cand; }
            }
        }
        idx = besti;
    }

    const float4* qrow  = (const float4*)(cb + (size_t)idx * D_);
    const float4* zrow4 = (const float4*)(z + (size_t)m * D_);
    float4*       orow  = (float4*)(out_zq + (size_t)m * D_);
    float lsum = 0.f;
    #pragma unroll
    for (int i = 0; i < 2; i++) {
        const int j = lane + i * 64;
        const float4 q  = qrow[j];
        const float4 zv = zrow4[j];
        float4 o;
        o.x = zv.x + (q.x - zv.x); o.y = zv.y + (q.y - zv.y);
        o.z = zv.z + (q.z - zv.z); o.w = zv.w + (q.w - zv.w);
        orow[j] = o;
        const float dx = zv.x - q.x, dy = zv.y - q.y, dz = zv.z - q.z, dw = zv.w - q.w;
        lsum += dx * dx + dy * dy + dz * dz + dw * dw;
    }
    #pragma unroll
    for (int msk = 1; msk < 64; msk <<= 1) lsum += __shfl_xor(lsum, msk, 64);

    if (lane == 0) {
        out_idx[m] = (float)idx;
        atomicAdd(&counts[idx], 1);
    }
    __shared__ float wl[4];
    if (lane == 0) wl[wid] = lsum;
    __syncthreads();
    if (threadIdx.x == 0) blockLoss[blockIdx.x] = wl[0] + wl[1] + wl[2] + wl[3];
}

// ---------------- kernel 4: scalars (loss, perplexity) ----------------
__global__ void vq_final_kernel(const int* __restrict__ counts,
                                const float* __restrict__ blockLoss,
                                float* __restrict__ out_loss, float* __restrict__ out_ppl) {
    __shared__ float sl[256], se[256];
    const int t = threadIdx.x;
    float ls = 0.f, es = 0.f;
    for (int i = t; i < N_ / 4; i += 256) ls += blockLoss[i];
    for (int k = t; k < K_; k += 256) {
        const float p = (float)counts[k] / (float)N_;
        es += p * logf(p + 1e-10f);
    }
    sl[t] = ls; se[t] = es;
    __syncthreads();
    for (int s = 128; s > 0; s >>= 1) {
        if (t < s) { sl[t] += sl[t + s]; se[t] += se[t + s]; }
        __syncthreads();
    }
    if (t == 0) {
        out_loss[0] = 0.25f * (sl[0] / (float)((size_t)N_ * D_));
        out_ppl[0]  = expf(-se[0]);
    }
}

extern "C" void kernel_launch(void* const* d_in, const int* in_sizes, int n_in,
                              void* d_out, int out_size, void* d_ws, size_t ws_size,
                              hipStream_t stream) {
    const float* z  = (const float*)d_in[0];
    const float* cb = (const float*)d_in[1];
    float* out = (float*)d_out;

    char* ws = (char*)d_ws;
    uint2*    pK        = (uint2*)   (ws + OFF_PK);
    float*    enorm     = (float*)   (ws + OFF_EN);
    float*    znorm     = (float*)   (ws + OFF_ZN);
    int*      counts    = (int*)     (ws + OFF_CNT);
    float*    blockLoss = (float*)   (ws + OFF_BL);
    _Float16* zh        = (_Float16*)(ws + OFF_ZH);
    _Float16* eh        = (_Float16*)(ws + OFF_EH);

    float* out_zq   = out;                         // [N_*D_]
    float* out_loss = out + (size_t)N_ * D_;       // [1]
    float* out_idx  = out_loss + 1;                // [N_]
    float* out_ppl  = out_idx + N_;                // [1]

    vq_prep_kernel<<<(N_ + K_) * 64 / 256, 256, 0, stream>>>(z, cb, zh, eh,
                                                             znorm, enorm, counts);

    dim3 grid(K_ / 128, N_ / 128);   // x = c-block fast: eh L2-resident
    vq_dist_kernel<<<grid, 256, 0, stream>>>(zh, eh, enorm, znorm, pK);

    vq_gather_kernel<<<N_ / 4, 256, 0, stream>>>(z, cb, znorm, enorm, pK,
                                                 out_zq, out_idx, counts, blockLoss);

    vq_final_kernel<<<1, 256, 0, stream>>>(counts, blockLoss, out_loss, out_ppl);
}